// Round 2
// baseline (436.661 us; speedup 1.0000x reference)
//
#include <hip/hip_runtime.h>
#include <math.h>

#define NPIX   131072      // 8*128*128
#define CCH    256
#define HW     16384       // 128*128
#define BSTR   4194304     // 256*16384 (features b-stride)
#define NUMC   21

// ---------------- kernel 1: pseudo labels + per-class counts ----------------
__global__ __launch_bounds__(256) void k_labels(const int* __restrict__ labels,
                                                const float* __restrict__ outputs_old,
                                                int* __restrict__ lab,
                                                float* __restrict__ gcnt)
{
    __shared__ float cnt[NUMC];
    if (threadIdx.x < NUMC) cnt[threadIdx.x] = 0.f;
    __syncthreads();

    int p = blockIdx.x * 256 + threadIdx.x;
    int b = p >> 14;
    int rem = p & 16383;
    int h = rem >> 7;
    int w = rem & 127;
    int ld = labels[b * 262144 + (h * 4) * 512 + (w * 4)];
    int out = ld;
    if (ld == 0) {
        const float* oo = outputs_old + (size_t)b * BSTR + (size_t)(h * 4) * 512 + (w * 4);
        float v0 = oo[0];
        float best = (v0 < 0.7f) ? 0.0f : v0;
        int bi = 0;
        #pragma unroll
        for (int c = 1; c < 16; ++c) {
            float v = oo[(size_t)c * 262144];
            v = (v < 0.7f) ? 0.0f : v;
            if (v > best) { best = v; bi = c; }   // strict > == first-occurrence argmax
        }
        out = bi;
    }
    lab[p] = out;
    atomicAdd(&cnt[out], 1.0f);
    __syncthreads();
    if (threadIdx.x < NUMC) unsafeAtomicAdd(&gcnt[threadIdx.x], cnt[threadIdx.x]);
}

// ---------------- kernel 2: partial sums of squares (px-chunk x ch-chunk) ----------------
// grid = 256 px-chunks * 8 ch-chunks = 2048 blocks -> 8 blocks/CU, 32 waves/CU.
__global__ __launch_bounds__(256) void k_norms(const float* __restrict__ fa,
                                               const float* __restrict__ fo,
                                               float* __restrict__ sumsqA,
                                               float* __restrict__ sumsqO)
{
    int pxc = blockIdx.x >> 3;          // 0..255
    int cc  = blockIdx.x & 7;           // 0..7
    int p0  = pxc * 512 + threadIdx.x * 2;
    int b   = p0 >> 14;
    int hw  = p0 & 16383;
    int c0  = cc * 32;
    const float* pa = fa + (size_t)b * BSTR + (size_t)c0 * HW + hw;
    const float* po = fo + (size_t)b * BSTR + (size_t)c0 * HW + hw;
    float sax = 0.f, say = 0.f, sox = 0.f, soy = 0.f;
    #pragma unroll 8
    for (int c = 0; c < 32; ++c) {
        float2 va = *(const float2*)(pa + (size_t)c * HW);
        float2 vo = *(const float2*)(po + (size_t)c * HW);
        sax += va.x * va.x; say += va.y * va.y;
        sox += vo.x * vo.x; soy += vo.y * vo.y;
    }
    unsafeAtomicAdd(&sumsqA[p0],     sax);
    unsafeAtomicAdd(&sumsqA[p0 + 1], say);
    unsafeAtomicAdd(&sumsqO[p0],     sox);
    unsafeAtomicAdd(&sumsqO[p0 + 1], soy);
}

// ---------------- kernel 3: per-class sums (px-chunk x ch-chunk) ----------------
// Small LDS accumulator per block (2 x 21 x 33 floats, padded: bank = (k+c)%32,
// distinct across classes for a fixed channel). Flush via device-scope fp32 atomics.
__global__ __launch_bounds__(256) void k_accum(const float* __restrict__ fa,
                                               const float* __restrict__ fo,
                                               const int* __restrict__ lab,
                                               const float* __restrict__ sumsqA,
                                               const float* __restrict__ sumsqO,
                                               float* __restrict__ gsumA,
                                               float* __restrict__ gsumO)
{
    __shared__ float accA[NUMC * 33];
    __shared__ float accO[NUMC * 33];
    for (int i = threadIdx.x; i < NUMC * 33; i += 256) { accA[i] = 0.f; accO[i] = 0.f; }
    __syncthreads();

    int pxc = blockIdx.x >> 3;
    int cc  = blockIdx.x & 7;
    int p0  = pxc * 512 + threadIdx.x * 2;
    int b   = p0 >> 14;
    int hw  = p0 & 16383;
    int c0  = cc * 32;

    int k0 = lab[p0];
    int k1 = lab[p0 + 1];
    float ia0 = 1.0f / fmaxf(sqrtf(sumsqA[p0]),     1e-12f);
    float ia1 = 1.0f / fmaxf(sqrtf(sumsqA[p0 + 1]), 1e-12f);
    float io0 = 1.0f / fmaxf(sqrtf(sumsqO[p0]),     1e-12f);
    float io1 = 1.0f / fmaxf(sqrtf(sumsqO[p0 + 1]), 1e-12f);

    const float* pa = fa + (size_t)b * BSTR + (size_t)c0 * HW + hw;
    const float* po = fo + (size_t)b * BSTR + (size_t)c0 * HW + hw;
    int k0b = k0 * 33, k1b = k1 * 33;
    #pragma unroll 4
    for (int c = 0; c < 32; ++c) {
        float2 va = *(const float2*)(pa + (size_t)c * HW);
        float2 vo = *(const float2*)(po + (size_t)c * HW);
        atomicAdd(&accA[k0b + c], va.x * ia0);
        atomicAdd(&accA[k1b + c], va.y * ia1);
        atomicAdd(&accO[k0b + c], vo.x * io0);
        atomicAdd(&accO[k1b + c], vo.y * io1);
    }
    __syncthreads();
    for (int i = threadIdx.x; i < NUMC * 32; i += 256) {
        int k = i >> 5, cl = i & 31;
        unsafeAtomicAdd(&gsumA[k * 256 + c0 + cl], accA[k * 33 + cl]);
        unsafeAtomicAdd(&gsumO[k * 256 + c0 + cl], accO[k * 33 + cl]);
    }
}

// ---------------- kernel 4: finalize (tiny) ----------------
__global__ __launch_bounds__(256) void k_final(const float* __restrict__ gsumA,
                                               const float* __restrict__ gsumO,
                                               const float* __restrict__ gcnt,
                                               float* __restrict__ out)
{
    __shared__ float anc[NUMC * 260];
    __shared__ float con[NUMC * 260];
    __shared__ float adc[NUMC * 44];
    __shared__ float cntS[NUMC];
    __shared__ float rowloss[NUMC];
    __shared__ float rowvalid[NUMC];

    if (threadIdx.x < NUMC) cntS[threadIdx.x] = gcnt[threadIdx.x];
    __syncthreads();
    for (int i = threadIdx.x; i < NUMC * 256; i += 256) {
        int k = i >> 8, c = i & 255;
        float cn = cntS[k];
        bool pr = cn > 0.f;
        float d = pr ? cn : 1.f;
        anc[k * 260 + c] = pr ? gsumA[i] / d : 0.f;
        con[k * 260 + c] = pr ? gsumO[i] / d : 0.f;
    }
    __syncthreads();
    // adc[k][j] = dot(anc_k, contrast_j)/T,  contrast = [anc; con]
    for (int pair = threadIdx.x; pair < NUMC * 2 * NUMC; pair += 256) {
        int k = pair / (2 * NUMC);
        int j = pair % (2 * NUMC);
        const float* ar = anc + k * 260;
        const float* br = (j < NUMC) ? (anc + j * 260) : (con + (j - NUMC) * 260);
        float s = 0.f;
        for (int c = 0; c < CCH; c += 4) {
            float4 a4 = *(const float4*)(ar + c);
            float4 b4 = *(const float4*)(br + c);
            s += a4.x * b4.x + a4.y * b4.y + a4.z * b4.z + a4.w * b4.w;
        }
        adc[k * 44 + j] = s / 0.07f;
    }
    __syncthreads();
    if (threadIdx.x < NUMC) {
        int k = threadIdx.x;
        bool pr = cntS[k] > 0.f;
        float neg = 0.f;       // faithful to source — negatives use UNshifted logits
        float mx = -1e30f;
        for (int j = 0; j < 2 * NUMC; ++j) {
            int cj = (j < NUMC) ? j : (j - NUMC);
            bool cp = cntS[cj] > 0.f;
            float v = adc[k * 44 + j];
            if (cp) {
                if (v > mx) mx = v;
                if (j != k && j != NUMC + k) neg += expf(v);
            }
        }
        float sh = adc[k * 44 + NUMC + k] - mx;
        float rl = -(sh - logf(expf(sh) + neg));
        rowloss[k] = pr ? rl : 0.f;
        rowvalid[k] = pr ? 1.f : 0.f;
    }
    __syncthreads();
    if (threadIdx.x == 0) {
        float s = 0.f, v = 0.f;
        for (int kk = 0; kk < NUMC; ++kk) { s += rowloss[kk]; v += rowvalid[kk]; }
        out[0] = s / fmaxf(v, 1.f);
    }
}

// ---------------- launch ----------------
extern "C" void kernel_launch(void* const* d_in, const int* in_sizes, int n_in,
                              void* d_out, int out_size, void* d_ws, size_t ws_size,
                              hipStream_t stream) {
    const int*   labels      = (const int*)  d_in[0];
    const float* feats_old   = (const float*)d_in[1];
    const float* feats       = (const float*)d_in[2];
    const float* outputs_old = (const float*)d_in[3];
    // d_in[4] (outputs) and d_in[5] (prototypes) are unused by the reference math.

    float* ws     = (float*)d_ws;
    int*   lab    = (int*)ws;                 // [131072]
    float* sumsqA = ws + 131072;              // [131072]
    float* sumsqO = ws + 262144;              // [131072]
    float* gsumA  = ws + 393216;              // [21*256]
    float* gsumO  = ws + 398592;              // [21*256]
    float* gcnt   = ws + 403968;              // [21]

    // zero sumsqA/sumsqO/gsumA/gsumO/gcnt (contiguous)
    hipMemsetAsync(sumsqA, 0, (size_t)(262144 + NUMC * 256 * 2 + NUMC) * sizeof(float), stream);

    k_labels<<<NPIX / 256, 256, 0, stream>>>(labels, outputs_old, lab, gcnt);
    k_norms <<<2048, 256, 0, stream>>>(feats, feats_old, sumsqA, sumsqO);
    k_accum <<<2048, 256, 0, stream>>>(feats, feats_old, lab, sumsqA, sumsqO,
                                       gsumA, gsumO);
    k_final <<<1, 256, 0, stream>>>(gsumA, gsumO, gcnt, (float*)d_out);
}

// Round 3
// 435.933 us; speedup vs baseline: 1.0017x; 1.0017x over previous
//
#include <hip/hip_runtime.h>
#include <math.h>

#define NPIX   131072      // 8*128*128
#define CCH    256
#define HW     16384       // 128*128
#define BSTR   4194304     // 256*16384 (features b-stride)
#define NUMC   21

// ---------------- kernel 1: pseudo labels + per-class counts ----------------
__global__ __launch_bounds__(256) void k_labels(const int* __restrict__ labels,
                                                const float* __restrict__ outputs_old,
                                                int* __restrict__ lab,
                                                float* __restrict__ gcnt)
{
    __shared__ float cnt[NUMC];
    if (threadIdx.x < NUMC) cnt[threadIdx.x] = 0.f;
    __syncthreads();

    int p = blockIdx.x * 256 + threadIdx.x;
    int b = p >> 14;
    int rem = p & 16383;
    int h = rem >> 7;
    int w = rem & 127;
    int ld = labels[b * 262144 + (h * 4) * 512 + (w * 4)];
    int out = ld;
    if (ld == 0) {
        const float* oo = outputs_old + (size_t)b * BSTR + (size_t)(h * 4) * 512 + (w * 4);
        float v0 = oo[0];
        float best = (v0 < 0.7f) ? 0.0f : v0;
        int bi = 0;
        #pragma unroll
        for (int c = 1; c < 16; ++c) {
            float v = oo[(size_t)c * 262144];
            v = (v < 0.7f) ? 0.0f : v;
            if (v > best) { best = v; bi = c; }   // strict > == first-occurrence argmax
        }
        out = bi;
    }
    lab[p] = out;
    unsafeAtomicAdd(&cnt[out], 1.0f);      // native ds_add_f32, not CAS loop
    __syncthreads();
    if (threadIdx.x < NUMC) unsafeAtomicAdd(&gcnt[threadIdx.x], cnt[threadIdx.x]);
}

// ---------------- kernel 2: partial sums of squares (px-chunk x ch-chunk) ----------------
// grid = 256 px-chunks * 8 ch-chunks = 2048 blocks -> 8 blocks/CU, 32 waves/CU.
__global__ __launch_bounds__(256) void k_norms(const float* __restrict__ fa,
                                               const float* __restrict__ fo,
                                               float* __restrict__ sumsqA,
                                               float* __restrict__ sumsqO)
{
    int pxc = blockIdx.x >> 3;          // 0..255
    int cc  = blockIdx.x & 7;           // 0..7
    int p0  = pxc * 512 + threadIdx.x * 2;
    int b   = p0 >> 14;
    int hw  = p0 & 16383;
    int c0  = cc * 32;
    const float* pa = fa + (size_t)b * BSTR + (size_t)c0 * HW + hw;
    const float* po = fo + (size_t)b * BSTR + (size_t)c0 * HW + hw;
    float sax = 0.f, say = 0.f, sox = 0.f, soy = 0.f;
    #pragma unroll 8
    for (int c = 0; c < 32; ++c) {
        float2 va = *(const float2*)(pa + (size_t)c * HW);
        float2 vo = *(const float2*)(po + (size_t)c * HW);
        sax += va.x * va.x; say += va.y * va.y;
        sox += vo.x * vo.x; soy += vo.y * vo.y;
    }
    unsafeAtomicAdd(&sumsqA[p0],     sax);
    unsafeAtomicAdd(&sumsqA[p0 + 1], say);
    unsafeAtomicAdd(&sumsqO[p0],     sox);
    unsafeAtomicAdd(&sumsqO[p0 + 1], soy);
}

// ---------------- kernel 3: per-class sums (px-chunk x ch-chunk) ----------------
// Small LDS accumulator per block (2 x 21 x 33 floats, padded: bank = (k+c)%32,
// distinct across classes for a fixed channel). All LDS adds are native ds_add_f32.
__global__ __launch_bounds__(256) void k_accum(const float* __restrict__ fa,
                                               const float* __restrict__ fo,
                                               const int* __restrict__ lab,
                                               const float* __restrict__ sumsqA,
                                               const float* __restrict__ sumsqO,
                                               float* __restrict__ gsumA,
                                               float* __restrict__ gsumO)
{
    __shared__ float accA[NUMC * 33];
    __shared__ float accO[NUMC * 33];
    for (int i = threadIdx.x; i < NUMC * 33; i += 256) { accA[i] = 0.f; accO[i] = 0.f; }
    __syncthreads();

    int pxc = blockIdx.x >> 3;
    int cc  = blockIdx.x & 7;
    int p0  = pxc * 512 + threadIdx.x * 2;
    int b   = p0 >> 14;
    int hw  = p0 & 16383;
    int c0  = cc * 32;

    int k0 = lab[p0];
    int k1 = lab[p0 + 1];
    float ia0 = 1.0f / fmaxf(sqrtf(sumsqA[p0]),     1e-12f);
    float ia1 = 1.0f / fmaxf(sqrtf(sumsqA[p0 + 1]), 1e-12f);
    float io0 = 1.0f / fmaxf(sqrtf(sumsqO[p0]),     1e-12f);
    float io1 = 1.0f / fmaxf(sqrtf(sumsqO[p0 + 1]), 1e-12f);

    const float* pa = fa + (size_t)b * BSTR + (size_t)c0 * HW + hw;
    const float* po = fo + (size_t)b * BSTR + (size_t)c0 * HW + hw;
    int k0b = k0 * 33, k1b = k1 * 33;
    #pragma unroll 4
    for (int c = 0; c < 32; ++c) {
        float2 va = *(const float2*)(pa + (size_t)c * HW);
        float2 vo = *(const float2*)(po + (size_t)c * HW);
        unsafeAtomicAdd(&accA[k0b + c], va.x * ia0);
        unsafeAtomicAdd(&accA[k1b + c], va.y * ia1);
        unsafeAtomicAdd(&accO[k0b + c], vo.x * io0);
        unsafeAtomicAdd(&accO[k1b + c], vo.y * io1);
    }
    __syncthreads();
    for (int i = threadIdx.x; i < NUMC * 32; i += 256) {
        int k = i >> 5, cl = i & 31;
        unsafeAtomicAdd(&gsumA[k * 256 + c0 + cl], accA[k * 33 + cl]);
        unsafeAtomicAdd(&gsumO[k * 256 + c0 + cl], accO[k * 33 + cl]);
    }
}

// ---------------- kernel 4: finalize (tiny) ----------------
__global__ __launch_bounds__(256) void k_final(const float* __restrict__ gsumA,
                                               const float* __restrict__ gsumO,
                                               const float* __restrict__ gcnt,
                                               float* __restrict__ out)
{
    __shared__ float anc[NUMC * 260];
    __shared__ float con[NUMC * 260];
    __shared__ float adc[NUMC * 44];
    __shared__ float cntS[NUMC];
    __shared__ float rowloss[NUMC];
    __shared__ float rowvalid[NUMC];

    if (threadIdx.x < NUMC) cntS[threadIdx.x] = gcnt[threadIdx.x];
    __syncthreads();
    for (int i = threadIdx.x; i < NUMC * 256; i += 256) {
        int k = i >> 8, c = i & 255;
        float cn = cntS[k];
        bool pr = cn > 0.f;
        float d = pr ? cn : 1.f;
        anc[k * 260 + c] = pr ? gsumA[i] / d : 0.f;
        con[k * 260 + c] = pr ? gsumO[i] / d : 0.f;
    }
    __syncthreads();
    // adc[k][j] = dot(anc_k, contrast_j)/T,  contrast = [anc; con]
    for (int pair = threadIdx.x; pair < NUMC * 2 * NUMC; pair += 256) {
        int k = pair / (2 * NUMC);
        int j = pair % (2 * NUMC);
        const float* ar = anc + k * 260;
        const float* br = (j < NUMC) ? (anc + j * 260) : (con + (j - NUMC) * 260);
        float s = 0.f;
        for (int c = 0; c < CCH; c += 4) {
            float4 a4 = *(const float4*)(ar + c);
            float4 b4 = *(const float4*)(br + c);
            s += a4.x * b4.x + a4.y * b4.y + a4.z * b4.z + a4.w * b4.w;
        }
        adc[k * 44 + j] = s / 0.07f;
    }
    __syncthreads();
    if (threadIdx.x < NUMC) {
        int k = threadIdx.x;
        bool pr = cntS[k] > 0.f;
        float neg = 0.f;       // faithful to source — negatives use UNshifted logits
        float mx = -1e30f;
        for (int j = 0; j < 2 * NUMC; ++j) {
            int cj = (j < NUMC) ? j : (j - NUMC);
            bool cp = cntS[cj] > 0.f;
            float v = adc[k * 44 + j];
            if (cp) {
                if (v > mx) mx = v;
                if (j != k && j != NUMC + k) neg += expf(v);
            }
        }
        float sh = adc[k * 44 + NUMC + k] - mx;
        float rl = -(sh - logf(expf(sh) + neg));
        rowloss[k] = pr ? rl : 0.f;
        rowvalid[k] = pr ? 1.f : 0.f;
    }
    __syncthreads();
    if (threadIdx.x == 0) {
        float s = 0.f, v = 0.f;
        for (int kk = 0; kk < NUMC; ++kk) { s += rowloss[kk]; v += rowvalid[kk]; }
        out[0] = s / fmaxf(v, 1.f);
    }
}

// ---------------- launch ----------------
extern "C" void kernel_launch(void* const* d_in, const int* in_sizes, int n_in,
                              void* d_out, int out_size, void* d_ws, size_t ws_size,
                              hipStream_t stream) {
    const int*   labels      = (const int*)  d_in[0];
    const float* feats_old   = (const float*)d_in[1];
    const float* feats       = (const float*)d_in[2];
    const float* outputs_old = (const float*)d_in[3];
    // d_in[4] (outputs) and d_in[5] (prototypes) are unused by the reference math.

    float* ws     = (float*)d_ws;
    int*   lab    = (int*)ws;                 // [131072]
    float* sumsqA = ws + 131072;              // [131072]
    float* sumsqO = ws + 262144;              // [131072]
    float* gsumA  = ws + 393216;              // [21*256]
    float* gsumO  = ws + 398592;              // [21*256]
    float* gcnt   = ws + 403968;              // [21]

    // zero sumsqA/sumsqO/gsumA/gsumO/gcnt (contiguous)
    hipMemsetAsync(sumsqA, 0, (size_t)(262144 + NUMC * 256 * 2 + NUMC) * sizeof(float), stream);

    k_labels<<<NPIX / 256, 256, 0, stream>>>(labels, outputs_old, lab, gcnt);
    k_norms <<<2048, 256, 0, stream>>>(feats, feats_old, sumsqA, sumsqO);
    k_accum <<<2048, 256, 0, stream>>>(feats, feats_old, lab, sumsqA, sumsqO,
                                       gsumA, gsumO);
    k_final <<<1, 256, 0, stream>>>(gsumA, gsumO, gcnt, (float*)d_out);
}